// Round 9
// baseline (168.870 us; speedup 1.0000x reference)
//
#include <hip/hip_runtime.h>
#include <cstdint>
#include <cstddef>

#define B_ 8
#define T_ 512
#define D_ 768
#define H_ 768
#define BT_ 4096
#define LN_EPS 1e-3f

typedef short bf16x8 __attribute__((ext_vector_type(8)));
typedef float f32x4 __attribute__((ext_vector_type(4)));

__device__ __forceinline__ ushort f2bf(float f) {
    union { float f; unsigned u; } x; x.f = f;
    unsigned r = (x.u + 0x7FFFu + ((x.u >> 16) & 1u)) >> 16;
    return (ushort)r;
}
__device__ __forceinline__ float bf2f(ushort u) {
    union { unsigned u; float f; } x; x.u = ((unsigned)u) << 16;
    return x.f;
}

#define GLOAD_LDS16(gp, lp)                                                        \
    __builtin_amdgcn_global_load_lds((const __attribute__((address_space(1))) void*)(gp), \
                                     (__attribute__((address_space(3))) void*)(lp), 16, 0, 0)

// ================= prep: ln_tmix (blocks 0..4095) + 7 weight transposes =================
struct PrepArgs {
    const float *x, *g, *b, *mk, *mv, *mr;
    ushort *xk, *xv, *xr;
    const float* ws[7];   // 5x 768x768, cm_key(768x3072), cm_value(3072x768)
    ushort* wd[7];
};

__global__ __launch_bounds__(256) void prep(PrepArgs a) {
    __shared__ float tl[32][33];
    __shared__ float red[4][4];
    int bid = blockIdx.x;
    const int tid = threadIdx.x;
    if (bid < BT_) {
        const int row = bid;
        const int t = row & (T_ - 1);
        const float* xc = a.x + (size_t)row * D_;
        const float* xp = a.x + (size_t)(row - 1) * D_;
        const float c0 = xc[tid], c1 = xc[tid + 256], c2 = xc[tid + 512];
        float p0 = 0.f, p1 = 0.f, p2 = 0.f;
        if (t > 0) { p0 = xp[tid]; p1 = xp[tid + 256]; p2 = xp[tid + 512]; }
        float sc = c0 + c1 + c2, qc = c0 * c0 + c1 * c1 + c2 * c2;
        float sp = p0 + p1 + p2, qp = p0 * p0 + p1 * p1 + p2 * p2;
        #pragma unroll
        for (int off = 32; off > 0; off >>= 1) {
            sc += __shfl_down(sc, off); qc += __shfl_down(qc, off);
            sp += __shfl_down(sp, off); qp += __shfl_down(qp, off);
        }
        const int wid = tid >> 6;
        if ((tid & 63) == 0) { red[wid][0] = sc; red[wid][1] = qc; red[wid][2] = sp; red[wid][3] = qp; }
        __syncthreads();
        sc = red[0][0] + red[1][0] + red[2][0] + red[3][0];
        qc = red[0][1] + red[1][1] + red[2][1] + red[3][1];
        sp = red[0][2] + red[1][2] + red[2][2] + red[3][2];
        qp = red[0][3] + red[1][3] + red[2][3] + red[3][3];
        const float mc = sc * (1.0f / D_);
        const float rc = rsqrtf(qc * (1.0f / D_) - mc * mc + LN_EPS);
        const float mp = sp * (1.0f / D_);
        const float rp = rsqrtf(qp * (1.0f / D_) - mp * mp + LN_EPS);
        const size_t base = (size_t)row * D_;
        const float cv[3] = {c0, c1, c2};
        const float pv[3] = {p0, p1, p2};
        #pragma unroll
        for (int s = 0; s < 3; ++s) {
            const int d = tid + s * 256;
            const float cn = (cv[s] - mc) * rc * a.g[d] + a.b[d];
            const float pn = (t > 0) ? ((pv[s] - mp) * rp * a.g[d] + a.b[d]) : 0.0f;
            float m;
            m = a.mk[d]; a.xk[base + d] = f2bf(cn * m + pn * (1.f - m));
            m = a.mv[d]; a.xv[base + d] = f2bf(cn * m + pn * (1.f - m));
            m = a.mr[d]; a.xr[base + d] = f2bf(cn * m + pn * (1.f - m));
        }
        return;
    }
    bid -= BT_;
    int z, K, N, n0, k0;
    if (bid < 2880) {
        z = bid / 576; const int i = bid % 576;
        K = 768; N = 768; n0 = (i % 24) * 32; k0 = (i / 24) * 32;
    } else if (bid < 2880 + 2304) {
        z = 5; const int i = bid - 2880;
        K = 768; N = 3072; n0 = (i % 96) * 32; k0 = (i / 96) * 32;
    } else {
        z = 6; const int i = bid - 2880 - 2304;
        K = 3072; N = 768; n0 = (i % 24) * 32; k0 = (i / 24) * 32;
    }
    const float* W = a.ws[z];
    ushort* WT = a.wd[z];
    const int tx = tid & 31, ty = tid >> 5;
    #pragma unroll
    for (int i = 0; i < 4; ++i)
        tl[ty + i * 8][tx] = W[(size_t)(k0 + ty + i * 8) * N + n0 + tx];
    __syncthreads();
    #pragma unroll
    for (int i = 0; i < 4; ++i)
        WT[(size_t)(n0 + ty + i * 8) * K + k0 + tx] = f2bf(tl[tx][ty + i * 8]);
}

// ---------------- fused LN2 + channel-mix: emits bf16 xk2/xr2 ----------------
__global__ __launch_bounds__(256) void ln_cmix(const float* __restrict__ in,
                                               ushort* __restrict__ xk2,
                                               ushort* __restrict__ xr2,
                                               const float* __restrict__ g,
                                               const float* __restrict__ b,
                                               const float* __restrict__ mk,
                                               const float* __restrict__ mr) {
    const int row = blockIdx.x;
    const int t = row & (T_ - 1);
    const float* xc = in + (size_t)row * D_;
    const float* xp = in + (size_t)(row - 1) * D_;
    const int tid = threadIdx.x;
    const float c0 = xc[tid], c1 = xc[tid + 256], c2 = xc[tid + 512];
    float p0 = 0.f, p1 = 0.f, p2 = 0.f;
    if (t > 0) { p0 = xp[tid]; p1 = xp[tid + 256]; p2 = xp[tid + 512]; }
    float sc = c0 + c1 + c2, qc = c0 * c0 + c1 * c1 + c2 * c2;
    float sp = p0 + p1 + p2, qp = p0 * p0 + p1 * p1 + p2 * p2;
    #pragma unroll
    for (int off = 32; off > 0; off >>= 1) {
        sc += __shfl_down(sc, off); qc += __shfl_down(qc, off);
        sp += __shfl_down(sp, off); qp += __shfl_down(qp, off);
    }
    __shared__ float red[4][4];
    const int wid = tid >> 6;
    if ((tid & 63) == 0) { red[wid][0] = sc; red[wid][1] = qc; red[wid][2] = sp; red[wid][3] = qp; }
    __syncthreads();
    sc = red[0][0] + red[1][0] + red[2][0] + red[3][0];
    qc = red[0][1] + red[1][1] + red[2][1] + red[3][1];
    sp = red[0][2] + red[1][2] + red[2][2] + red[3][2];
    qp = red[0][3] + red[1][3] + red[2][3] + red[3][3];
    const float mc = sc * (1.0f / D_);
    const float rc = rsqrtf(qc * (1.0f / D_) - mc * mc + LN_EPS);
    const float mp = sp * (1.0f / D_);
    const float rp = rsqrtf(qp * (1.0f / D_) - mp * mp + LN_EPS);
    const size_t base = (size_t)row * D_;
    const float cv[3] = {c0, c1, c2};
    const float pv[3] = {p0, p1, p2};
    #pragma unroll
    for (int s = 0; s < 3; ++s) {
        const int d = tid + s * 256;
        const float cn = (cv[s] - mc) * rc * g[d] + b[d];
        const float pn = (t > 0) ? ((pv[s] - mp) * rp * g[d] + b[d]) : 0.0f;
        float m;
        m = mk[d]; xk2[base + d] = f2bf(cn * m + pn * (1.f - m));
        m = mr[d]; xr2[base + d] = f2bf(cn * m + pn * (1.f - m));
    }
}

// ---------------- WKV: chunked parallel scan over T (bf16 in, bf16 out) ----------------
#define WKV_CH 16
#define WKV_NC 16
#define WKV_L  32

__global__ __launch_bounds__(256) void wkv_scan(const ushort* __restrict__ k,
                                                const ushort* __restrict__ v,
                                                const ushort* __restrict__ srr,
                                                const float* __restrict__ time_decay,
                                                const float* __restrict__ time_first,
                                                ushort* __restrict__ rv) {
    const int c   = threadIdx.x & (WKV_CH - 1);
    const int ch  = threadIdx.x >> 4;
    const int gch = blockIdx.x * WKV_CH + c;
    const int b = gch / H_;
    const int h = gch % H_;
    const float ed = expf(time_decay[h]);
    const float tf = time_first[h];
    const size_t base = (size_t)b * T_ * H_ + h;

    float n = 0.f, d = 0.f, m = -1e30f;
    size_t idx = base + (size_t)(ch * WKV_L) * H_;
    #pragma unroll 4
    for (int t = 0; t < WKV_L; ++t, idx += H_) {
        const float kk = bf2f(k[idx]), vv = bf2f(v[idx]);
        const float w2 = m - ed;
        const float qn = fmaxf(w2, kk);
        const float e1 = expf(w2 - qn), e2 = expf(kk - qn);
        n = e1 * n + e2 * vv;
        d = e1 * d + e2;
        m = qn;
    }

    __shared__ float sn[WKV_NC][WKV_CH], sd[WKV_NC][WKV_CH], sm[WKV_NC][WKV_CH];
    sn[ch][c] = n; sd[ch][c] = d; sm[ch][c] = m;
    __syncthreads();

    if (ch == 0) {
        float pn = 0.f, pd = 0.f, pm = -1e30f;
        #pragma unroll
        for (int j = 0; j < WKV_NC; ++j) {
            const float nn = sn[j][c], dd = sd[j][c], m2 = sm[j][c];
            sn[j][c] = pn; sd[j][c] = pd; sm[j][c] = pm;
            const float w2 = pm - ed * (float)WKV_L;
            const float mm = fmaxf(w2, m2);
            const float e1 = expf(w2 - mm), e2 = expf(m2 - mm);
            pn = e1 * pn + e2 * nn;
            pd = e1 * pd + e2 * dd;
            pm = mm;
        }
    }
    __syncthreads();

    n = sn[ch][c]; d = sd[ch][c]; m = sm[ch][c];
    idx = base + (size_t)(ch * WKV_L) * H_;
    #pragma unroll 4
    for (int t = 0; t < WKV_L; ++t, idx += H_) {
        const float kk = bf2f(k[idx]), vv = bf2f(v[idx]), ss = bf2f(srr[idx]);
        const float w  = tf + kk;
        const float qq = fmaxf(m, w);
        const float e1 = expf(m - qq), e2 = expf(w - qq);
        const float wkvv = (e1 * n + e2 * vv) / (e1 * d + e2);
        rv[idx] = f2bf(ss * wkvv);
        const float w2 = m - ed;
        const float qn = fmaxf(w2, kk);
        const float a  = expf(w2 - qn), bb = expf(kk - qn);
        n = a * n + bb * vv;
        d = a * d + bb;
        m = qn;
    }
}

// ================= GEMM core (2-barrier dbuf, m97 structure) — KVR / RELU2 =================
template <int BM, int NF>
__device__ __forceinline__ void run_gemm(const ushort* __restrict__ A,
                                         const ushort* __restrict__ Bt,
                                         int K, int bm, int bn,
                                         ushort* As, ushort* Bs,
                                         f32x4 (&acc)[BM / 32][NF], int t) {
    constexpr int MF = BM / 32;
    constexpr int BN = NF * 32;
    constexpr int ASTRIDE = BM * 64;
    constexpr int BSTRIDE = BN * 64;
    const int l = t & 63, wid = t >> 6;
    const int wr = wid >> 1, wc = wid & 1;
    const int lr = l & 15, lg = l >> 4;
    const int l8 = l >> 3, j8 = l & 7;
    const int gcol = ((j8 ^ l8) << 3);
    const int rsw = lr & 7;

    auto STAGE = [&](int buf, int k0) {
        #pragma unroll
        for (int p = 0; p < MF; ++p) {
            const int r = wid * (BM / 4) + p * 8 + l8;
            GLOAD_LDS16(A + (size_t)(bm + r) * K + k0 + gcol,
                        As + buf * ASTRIDE + (wid * (BM / 4) + p * 8) * 64);
        }
        #pragma unroll
        for (int p = 0; p < NF; ++p) {
            const int r = wid * (BN / 4) + p * 8 + l8;
            GLOAD_LDS16(Bt + (size_t)(bn + r) * K + k0 + gcol,
                        Bs + buf * BSTRIDE + (wid * (BN / 4) + p * 8) * 64);
        }
    };

    STAGE(0, 0);
    const int nt = K >> 6;
    int cur = 0;
    for (int it = 0; it < nt; ++it) {
        if (it + 1 < nt) {
            STAGE(cur ^ 1, (it + 1) << 6);
            constexpr int VC = MF + NF;   // just-issued stage stays in flight
            if constexpr (VC == 4)      asm volatile("s_waitcnt vmcnt(4)" ::: "memory");
            else if constexpr (VC == 5) asm volatile("s_waitcnt vmcnt(5)" ::: "memory");
            else if constexpr (VC == 6) asm volatile("s_waitcnt vmcnt(6)" ::: "memory");
            else                        asm volatile("s_waitcnt vmcnt(8)" ::: "memory");
        } else {
            asm volatile("s_waitcnt vmcnt(0)" ::: "memory");
        }
        __builtin_amdgcn_sched_barrier(0);
        __builtin_amdgcn_s_barrier();
        const ushort* Ab = As + cur * ASTRIDE;
        const ushort* Bb = Bs + cur * BSTRIDE;
        #pragma unroll
        for (int ks = 0; ks < 2; ++ks) {
            const int cidx = ((ks * 4 + lg) ^ rsw) << 3;
            bf16x8 af[MF], bfr[NF];
            #pragma unroll
            for (int mf = 0; mf < MF; ++mf)
                af[mf] = *(const bf16x8*)(Ab + (wr * (BM / 2) + mf * 16 + lr) * 64 + cidx);
            #pragma unroll
            for (int nf = 0; nf < NF; ++nf)
                bfr[nf] = *(const bf16x8*)(Bb + (wc * (BN / 2) + nf * 16 + lr) * 64 + cidx);
            #pragma unroll
            for (int mf = 0; mf < MF; ++mf)
                #pragma unroll
                for (int nf = 0; nf < NF; ++nf)
                    acc[mf][nf] = __builtin_amdgcn_mfma_f32_16x16x32_bf16(
                        af[mf], bfr[nf], acc[mf][nf], 0, 0, 0);
        }
        __builtin_amdgcn_s_barrier();   // readers done before next iter overwrites
        cur ^= 1;
    }
}

// ================= single-barrier triple-buffered core (64x64, 4-wave: ADDX) ==========
template <int BM, int NF>
__device__ __forceinline__ void run_gemm_sb(const ushort* __restrict__ A,
                                            const ushort* __restrict__ Bt,
                                            int K, int bm, int bn,
                                            ushort* As, ushort* Bs,
                                            f32x4 (&acc)[BM / 32][NF], int t) {
    constexpr int MF = BM / 32;
    constexpr int BN = NF * 32;
    constexpr int ASTRIDE = BM * 64;
    constexpr int BSTRIDE = BN * 64;
    const int l = t & 63, wid = t >> 6;
    const int wr = wid >> 1, wc = wid & 1;
    const int lr = l & 15, lg = l >> 4;
    const int l8 = l >> 3, j8 = l & 7;
    const int gcol = ((j8 ^ l8) << 3);
    const int rsw = lr & 7;

    auto STAGE = [&](int buf, int k0) {
        #pragma unroll
        for (int p = 0; p < MF; ++p) {
            const int r = wid * (BM / 4) + p * 8 + l8;
            GLOAD_LDS16(A + (size_t)(bm + r) * K + k0 + gcol,
                        As + buf * ASTRIDE + (wid * (BM / 4) + p * 8) * 64);
        }
        #pragma unroll
        for (int p = 0; p < NF; ++p) {
            const int r = wid * (BN / 4) + p * 8 + l8;
            GLOAD_LDS16(Bt + (size_t)(bn + r) * K + k0 + gcol,
                        Bs + buf * BSTRIDE + (wid * (BN / 4) + p * 8) * 64);
        }
    };

    STAGE(0, 0);
    const int nt = K >> 6;
    int cur = 0;
    for (int it = 0; it < nt; ++it) {
        if (it + 1 < nt) {
            int nb = cur + 1; if (nb == 3) nb = 0;
            STAGE(nb, (it + 1) << 6);
            constexpr int VC = MF + NF;
            if constexpr (VC == 4)      asm volatile("s_waitcnt vmcnt(4)" ::: "memory");
            else if constexpr (VC == 5) asm volatile("s_waitcnt vmcnt(5)" ::: "memory");
            else if constexpr (VC == 6) asm volatile("s_waitcnt vmcnt(6)" ::: "memory");
            else                        asm volatile("s_waitcnt vmcnt(8)" ::: "memory");
        } else {
            asm volatile("s_waitcnt vmcnt(0)" ::: "memory");
        }
        __builtin_amdgcn_sched_barrier(0);
        __builtin_amdgcn_s_barrier();
        __builtin_amdgcn_sched_barrier(0);   // pin ds_reads after the rendezvous
        const ushort* Ab = As + cur * ASTRIDE;
        const ushort* Bb = Bs + cur * BSTRIDE;
        #pragma unroll
        for (int ks = 0; ks < 2; ++ks) {
            const int cidx = ((ks * 4 + lg) ^ rsw) << 3;
            bf16x8 af[MF], bfr[NF];
            #pragma unroll
            for (int mf = 0; mf < MF; ++mf)
                af[mf] = *(const bf16x8*)(Ab + (wr * (BM / 2) + mf * 16 + lr) * 64 + cidx);
            #pragma unroll
            for (int nf = 0; nf < NF; ++nf)
                bfr[nf] = *(const bf16x8*)(Bb + (wc * (BN / 2) + nf * 16 + lr) * 64 + cidx);
            #pragma unroll
            for (int mf = 0; mf < MF; ++mf)
                #pragma unroll
                for (int nf = 0; nf < NF; ++nf)
                    acc[mf][nf] = __builtin_amdgcn_mfma_f32_16x16x32_bf16(
                        af[mf], bfr[nf], acc[mf][nf], 0, 0, 0);
        }
        cur += 1; if (cur == 3) cur = 0;
    }
}

// ======== 2-wave single-barrier 3-buf core (64x64 block, wave-tile 64x32) ========
// 128 threads. Per iter per wave: 2ks x (4 A-reads + 2 B-reads) = 12 ds_read_b128
// for 16 MFMAs -> block LDS reads 32->24 KB/iter (total 48->40 KB with staging).
// Same per-lane XOR involution as the 4-wave cores (rows mf*16+lr, chunk
// (ks*4+lg)^(lr&7)) -> measured-zero bank conflicts carry over. Grid unchanged.
template <int NF>
__device__ __forceinline__ void run_gemm_2w(const ushort* __restrict__ A,
                                            const ushort* __restrict__ Bt,
                                            int K, int bm, int bn,
                                            ushort* As, ushort* Bs,
                                            f32x4 (&acc)[4][NF], int t) {
    constexpr int BN = NF * 32;          // 64
    constexpr int ASTRIDE = 64 * 64;
    constexpr int BSTRIDE = BN * 64;
    const int l = t & 63, wid = t >> 6;  // wid in {0,1}
    const int lr = l & 15, lg = l >> 4;
    const int l8 = l >> 3, j8 = l & 7;
    const int gcol = ((j8 ^ l8) << 3);
    const int rsw = lr & 7;

    auto STAGE = [&](int buf, int k0) {
        #pragma unroll
        for (int p = 0; p < 4; ++p) {    // A: 64 rows, 16 rows per 2-wave call
            const int r = p * 16 + wid * 8 + l8;
            GLOAD_LDS16(A + (size_t)(bm + r) * K + k0 + gcol,
                        As + buf * ASTRIDE + (p * 16 + wid * 8) * 64);
        }
        #pragma unroll
        for (int p = 0; p < 4; ++p) {    // B: 64 rows
            const int r = p * 16 + wid * 8 + l8;
            GLOAD_LDS16(Bt + (size_t)(bn + r) * K + k0 + gcol,
                        Bs + buf * BSTRIDE + (p * 16 + wid * 8) * 64);
        }
    };

    STAGE(0, 0);
    const int nt = K >> 6;
    int cur = 0;
    for (int it = 0; it < nt; ++it) {
        if (it + 1 < nt) {
            int nb = cur + 1; if (nb == 3) nb = 0;
            STAGE(nb, (it + 1) << 6);
            asm volatile("s_waitcnt vmcnt(8)" ::: "memory");   // just-issued stage in flight
        } else {
            asm volatile("s_waitcnt vmcnt(0)" ::: "memory");
        }
        __builtin_amdgcn_sched_barrier(0);
        __builtin_amdgcn_s_barrier();
        __builtin_amdgcn_sched_barrier(0);   // pin ds_reads after the rendezvous
        const ushort* Ab = As + cur * ASTRIDE;
        const ushort* Bb = Bs + cur * BSTRIDE;
        #pragma unroll
        for (int ks = 0; ks < 2; ++ks) {
            const int cidx = ((ks * 4 + lg) ^ rsw) << 3;
            bf16x8 af[4], bfr[NF];
            #pragma unroll
            for (int mf = 0; mf < 4; ++mf)
                af[mf] = *(const bf16x8*)(Ab + (mf * 16 + lr) * 64 + cidx);
            #pragma unroll
            for (int nf = 0; nf < NF; ++nf)
                bfr[nf] = *(const bf16x8*)(Bb + (wid * 32 + nf * 16 + lr) * 64 + cidx);
            #pragma unroll
            for (int mf = 0; mf < 4; ++mf)
                #pragma unroll
                for (int nf = 0; nf < NF; ++nf)
                    acc[mf][nf] = __builtin_amdgcn_mfma_f32_16x16x32_bf16(
                        af[mf], bfr[nf], acc[mf][nf], 0, 0, 0);
        }
        cur += 1; if (cur == 3) cur = 0;
    }
}

enum { EPI_KVR = 0, EPI_ADDX = 1, EPI_RELU2 = 2 };

template <int EPI, int BM, int BN>
__global__ __launch_bounds__(256) void hgemm(const ushort* __restrict__ Abase,
                                             const ushort* __restrict__ Wbase,
                                             void* __restrict__ Cbase,
                                             const float* __restrict__ aux1,
                                             int M, int N, int K) {
    constexpr int NF = BN / 32;
    constexpr int MF = BM / 32;
    constexpr bool SB = (BN == 64);          // single-barrier 3-buf for 64x64
    __shared__ __align__(16) ushort As[(SB ? 3 : 2) * BM * 64];
    __shared__ __align__(16) ushort Bs[(SB ? 3 : 2) * BN * 64];
    const int t = threadIdx.x;
    int lin = blockIdx.y * gridDim.x + blockIdx.x;
    const int q = (gridDim.x * gridDim.y) >> 3;
    lin = (lin & 7) * q + (lin >> 3);
    const int bn = (lin % gridDim.x) * BN;
    const int bm = (lin / gridDim.x) * BM;
    const int z = blockIdx.z;

    const ushort* A  = Abase;
    const ushort* Bt = Wbase;
    float*  Cf = (float*)Cbase;
    ushort* Cu = (ushort*)Cbase;
    if (EPI == EPI_KVR) {
        A  += (size_t)z * ((size_t)M * K);
        Bt += (size_t)z * ((size_t)N * K);
        Cu += (size_t)z * ((size_t)M * N);
    }

    f32x4 acc[MF][NF];
    #pragma unroll
    for (int i = 0; i < MF; ++i)
        #pragma unroll
        for (int j = 0; j < NF; ++j) acc[i][j] = (f32x4){0.f, 0.f, 0.f, 0.f};

    if constexpr (SB)
        run_gemm_sb<BM, NF>(A, Bt, K, bm, bn, As, Bs, acc, t);
    else
        run_gemm<BM, NF>(A, Bt, K, bm, bn, As, Bs, acc, t);

    const int l = t & 63, wid = t >> 6;
    const int wr = wid >> 1, wc = wid & 1;
    const int lr = l & 15, lg = l >> 4;
    #pragma unroll
    for (int mf = 0; mf < MF; ++mf) {
        #pragma unroll
        for (int nf = 0; nf < NF; ++nf) {
            const f32x4 a = acc[mf][nf];
            #pragma unroll
            for (int j = 0; j < 4; ++j) {
                const int row = bm + wr * (BM / 2) + mf * 16 + lg * 4 + j;
                const int col = bn + wc * (BN / 2) + nf * 16 + lr;
                const size_t idx = (size_t)row * N + col;
                const float vacc = a[j];
                if (EPI == EPI_KVR) {
                    Cu[idx] = f2bf((z == 2) ? 1.0f / (1.0f + expf(-vacc)) : vacc);
                } else if (EPI == EPI_ADDX) {
                    Cf[idx] = aux1[idx] + vacc;
                } else {  // EPI_RELU2
                    const float r = fmaxf(vacc, 0.0f);
                    Cu[idx] = f2bf(r * r);
                }
            }
        }
    }
}

// ---- fused: out = ymid + sigmoid(xr2 @ WcR) * (h1 @ WcV) ----
// 2-wave (128-thread) 64x64 blocks, wave-tile 64x32: LDS traffic 48->40 KB/iter.
// Grid stays 768 (3 blocks/CU), LDS 48 KB (3-buf single-barrier).
__global__ __launch_bounds__(128) void kv_sigmul(const ushort* __restrict__ h1,
                                                 const ushort* __restrict__ wtCV,
                                                 const ushort* __restrict__ xr2,
                                                 const ushort* __restrict__ wtCR,
                                                 const float* __restrict__ ymid,
                                                 float* __restrict__ out) {
    __shared__ __align__(16) ushort As[3 * 64 * 64];
    __shared__ __align__(16) ushort Bs[3 * 64 * 64];
    const int t = threadIdx.x;
    int lin = blockIdx.y * gridDim.x + blockIdx.x;
    const int q = (gridDim.x * gridDim.y) >> 3;
    lin = (lin & 7) * q + (lin >> 3);
    const int bn = (lin % gridDim.x) * 64;
    const int bm = (lin / gridDim.x) * 64;

    f32x4 acc1[4][2], acc2[4][2];
    #pragma unroll
    for (int i = 0; i < 4; ++i)
        #pragma unroll
        for (int j = 0; j < 2; ++j) {
            acc1[i][j] = (f32x4){0.f, 0.f, 0.f, 0.f};
            acc2[i][j] = (f32x4){0.f, 0.f, 0.f, 0.f};
        }

    run_gemm_2w<2>(h1, wtCV, 3072, bm, bn, As, Bs, acc1, t);   // kv
    __syncthreads();   // isolate buffer reuse between the two GEMMs
    run_gemm_2w<2>(xr2, wtCR, 768, bm, bn, As, Bs, acc2, t);   // recept

    const int l = t & 63, wid = t >> 6;
    const int lr = l & 15, lg = l >> 4;
    #pragma unroll
    for (int mf = 0; mf < 4; ++mf) {
        #pragma unroll
        for (int nf = 0; nf < 2; ++nf) {
            #pragma unroll
            for (int j = 0; j < 4; ++j) {
                const int row = bm + mf * 16 + lg * 4 + j;
                const int col = bn + wid * 32 + nf * 16 + lr;
                const size_t idx = (size_t)row * D_ + col;
                const float sig = 1.0f / (1.0f + expf(-acc2[mf][nf][j]));
                out[idx] = ymid[idx] + sig * acc1[mf][nf][j];
            }
        }
    }
}

extern "C" void kernel_launch(void* const* d_in, const int* in_sizes, int n_in,
                              void* d_out, int out_size, void* d_ws, size_t ws_size,
                              hipStream_t stream) {
    const float* x          = (const float*)d_in[0];
    const float* ln1_g      = (const float*)d_in[1];
    const float* ln1_b      = (const float*)d_in[2];
    const float* ln2_g      = (const float*)d_in[3];
    const float* ln2_b      = (const float*)d_in[4];
    const float* tm_mix_k   = (const float*)d_in[5];
    const float* tm_mix_v   = (const float*)d_in[6];
    const float* tm_mix_r   = (const float*)d_in[7];
    const float* tm_key_w   = (const float*)d_in[8];
    const float* tm_value_w = (const float*)d_in[9];
    const float* tm_rec_w   = (const float*)d_in[10];
    const float* time_decay = (const float*)d_in[11];
    const float* time_first = (const float*)d_in[12];
    const float* out_w      = (const float*)d_in[13];
    const float* cm_mix_k   = (const float*)d_in[14];
    const float* cm_mix_r   = (const float*)d_in[15];
    const float* cm_key_w   = (const float*)d_in[16];
    const float* cm_value_w = (const float*)d_in[17];
    const float* cm_rec_w   = (const float*)d_in[18];
    float* out = (float*)d_out;

    const size_t SZ = (size_t)BT_ * D_;
    float* wsf = (float*)d_ws;
    float* ymid = wsf;                  // [BT,D] fp32
    ushort* ub = (ushort*)(wsf + SZ);
    ushort* a0 = ub;                    // xk, later rv
    ushort* a1 = ub + SZ;               // xv, later xk2
    ushort* a2 = ub + 2 * SZ;           // xr, later xr2
    ushort* h1 = ub + 3 * SZ;           // [BT,3072] bf16
    ushort* kvsr = ub + 7 * SZ;         // k,v,sr bf16 [3][BT*H]
    ushort* wt = ub + 10 * SZ;
    const size_t W66  = (size_t)768 * 768;
    const size_t WBIG = (size_t)768 * 3072;
    ushort* wtK  = wt;
    ushort* wtV  = wt + W66;
    ushort* wtR  = wt + 2 * W66;
    ushort* wtO  = wt + 3 * W66;
    ushort* wtCR = wt + 4 * W66;
    ushort* wtCK = wt + 5 * W66;        // [3072][768]
    ushort* wtCV = wt + 5 * W66 + WBIG; // [768][3072]

    PrepArgs pa;
    pa.x = x; pa.g = ln1_g; pa.b = ln1_b;
    pa.mk = tm_mix_k; pa.mv = tm_mix_v; pa.mr = tm_mix_r;
    pa.xk = a0; pa.xv = a1; pa.xr = a2;
    pa.ws[0] = tm_key_w;   pa.wd[0] = wtK;
    pa.ws[1] = tm_value_w; pa.wd[1] = wtV;
    pa.ws[2] = tm_rec_w;   pa.wd[2] = wtR;
    pa.ws[3] = out_w;      pa.wd[3] = wtO;
    pa.ws[4] = cm_rec_w;   pa.wd[4] = wtCR;
    pa.ws[5] = cm_key_w;   pa.wd[5] = wtCK;
    pa.ws[6] = cm_value_w; pa.wd[6] = wtCV;

    // 1. prep: LN1+time-mix + all weight transposes (one dispatch)
    prep<<<BT_ + 2880 + 2304 + 2304, 256, 0, stream>>>(pa);
    // 2. fused k/v/sr GEMM (z=0,1,2), bf16 out   [64x128 tile: grid 6x64x3 = 1152]
    hgemm<EPI_KVR, 64, 128><<<dim3(6, 64, 3), 256, 0, stream>>>(a0, wtK, kvsr, nullptr, BT_, 768, 768);
    // 3. WKV parallel scan -> rv = sr*wkv (bf16)
    wkv_scan<<<(B_ * H_) / WKV_CH, 256, 0, stream>>>(kvsr, kvsr + SZ, kvsr + 2 * SZ,
                                                     time_decay, time_first, a0);
    // 4. y_mid = x + rv @ out_w                   [grid 768, 64x64 single-barrier]
    hgemm<EPI_ADDX, 64, 64><<<dim3(12, 64), 256, 0, stream>>>(a0, wtO, ymid, x, BT_, 768, 768);
    // 5. LN2 + channel-mix -> bf16 xk2/xr2
    ln_cmix<<<BT_, 256, 0, stream>>>(ymid, a1, a2, ln2_g, ln2_b, cm_mix_k, cm_mix_r);
    // 6. h1 = relu(xk2 @ cm_key)^2 (bf16)         [grid 24x64 = 1536, 64x128 dbuf]
    hgemm<EPI_RELU2, 64, 128><<<dim3(24, 64), 256, 0, stream>>>(a1, wtCK, h1, nullptr, BT_, 3072, 768);
    // 7. out = y_mid + sigmoid(xr2 @ cm_rec) * (h1 @ cm_value)   [grid 12x64 = 768, 128 thr]
    kv_sigmul<<<dim3(12, 64), 128, 0, stream>>>(h1, wtCV, a2, wtCR, ymid, out);
}

// Round 10
// 159.994 us; speedup vs baseline: 1.0555x; 1.0555x over previous
//
#include <hip/hip_runtime.h>
#include <cstdint>
#include <cstddef>

#define B_ 8
#define T_ 512
#define D_ 768
#define H_ 768
#define BT_ 4096
#define LN_EPS 1e-3f

typedef short bf16x8 __attribute__((ext_vector_type(8)));
typedef float f32x4 __attribute__((ext_vector_type(4)));

__device__ __forceinline__ ushort f2bf(float f) {
    union { float f; unsigned u; } x; x.f = f;
    unsigned r = (x.u + 0x7FFFu + ((x.u >> 16) & 1u)) >> 16;
    return (ushort)r;
}
__device__ __forceinline__ float bf2f(ushort u) {
    union { unsigned u; float f; } x; x.u = ((unsigned)u) << 16;
    return x.f;
}

#define GLOAD_LDS16(gp, lp)                                                        \
    __builtin_amdgcn_global_load_lds((const __attribute__((address_space(1))) void*)(gp), \
                                     (__attribute__((address_space(3))) void*)(lp), 16, 0, 0)

// ================= prep: ln_tmix (blocks 0..4095) + 7 weight transposes =================
struct PrepArgs {
    const float *x, *g, *b, *mk, *mv, *mr;
    ushort *xk, *xv, *xr;
    const float* ws[7];   // 5x 768x768, cm_key(768x3072), cm_value(3072x768)
    ushort* wd[7];
};

__global__ __launch_bounds__(256) void prep(PrepArgs a) {
    __shared__ float tl[32][33];
    __shared__ float red[4][4];
    int bid = blockIdx.x;
    const int tid = threadIdx.x;
    if (bid < BT_) {
        const int row = bid;
        const int t = row & (T_ - 1);
        const float* xc = a.x + (size_t)row * D_;
        const float* xp = a.x + (size_t)(row - 1) * D_;
        const float c0 = xc[tid], c1 = xc[tid + 256], c2 = xc[tid + 512];
        float p0 = 0.f, p1 = 0.f, p2 = 0.f;
        if (t > 0) { p0 = xp[tid]; p1 = xp[tid + 256]; p2 = xp[tid + 512]; }
        float sc = c0 + c1 + c2, qc = c0 * c0 + c1 * c1 + c2 * c2;
        float sp = p0 + p1 + p2, qp = p0 * p0 + p1 * p1 + p2 * p2;
        #pragma unroll
        for (int off = 32; off > 0; off >>= 1) {
            sc += __shfl_down(sc, off); qc += __shfl_down(qc, off);
            sp += __shfl_down(sp, off); qp += __shfl_down(qp, off);
        }
        const int wid = tid >> 6;
        if ((tid & 63) == 0) { red[wid][0] = sc; red[wid][1] = qc; red[wid][2] = sp; red[wid][3] = qp; }
        __syncthreads();
        sc = red[0][0] + red[1][0] + red[2][0] + red[3][0];
        qc = red[0][1] + red[1][1] + red[2][1] + red[3][1];
        sp = red[0][2] + red[1][2] + red[2][2] + red[3][2];
        qp = red[0][3] + red[1][3] + red[2][3] + red[3][3];
        const float mc = sc * (1.0f / D_);
        const float rc = rsqrtf(qc * (1.0f / D_) - mc * mc + LN_EPS);
        const float mp = sp * (1.0f / D_);
        const float rp = rsqrtf(qp * (1.0f / D_) - mp * mp + LN_EPS);
        const size_t base = (size_t)row * D_;
        const float cv[3] = {c0, c1, c2};
        const float pv[3] = {p0, p1, p2};
        #pragma unroll
        for (int s = 0; s < 3; ++s) {
            const int d = tid + s * 256;
            const float cn = (cv[s] - mc) * rc * a.g[d] + a.b[d];
            const float pn = (t > 0) ? ((pv[s] - mp) * rp * a.g[d] + a.b[d]) : 0.0f;
            float m;
            m = a.mk[d]; a.xk[base + d] = f2bf(cn * m + pn * (1.f - m));
            m = a.mv[d]; a.xv[base + d] = f2bf(cn * m + pn * (1.f - m));
            m = a.mr[d]; a.xr[base + d] = f2bf(cn * m + pn * (1.f - m));
        }
        return;
    }
    bid -= BT_;
    int z, K, N, n0, k0;
    if (bid < 2880) {
        z = bid / 576; const int i = bid % 576;
        K = 768; N = 768; n0 = (i % 24) * 32; k0 = (i / 24) * 32;
    } else if (bid < 2880 + 2304) {
        z = 5; const int i = bid - 2880;
        K = 768; N = 3072; n0 = (i % 96) * 32; k0 = (i / 96) * 32;
    } else {
        z = 6; const int i = bid - 2880 - 2304;
        K = 3072; N = 768; n0 = (i % 24) * 32; k0 = (i / 24) * 32;
    }
    const float* W = a.ws[z];
    ushort* WT = a.wd[z];
    const int tx = tid & 31, ty = tid >> 5;
    #pragma unroll
    for (int i = 0; i < 4; ++i)
        tl[ty + i * 8][tx] = W[(size_t)(k0 + ty + i * 8) * N + n0 + tx];
    __syncthreads();
    #pragma unroll
    for (int i = 0; i < 4; ++i)
        WT[(size_t)(n0 + ty + i * 8) * K + k0 + tx] = f2bf(tl[tx][ty + i * 8]);
}

// ---------------- fused LN2 + channel-mix: emits bf16 xk2/xr2 ----------------
__global__ __launch_bounds__(256) void ln_cmix(const float* __restrict__ in,
                                               ushort* __restrict__ xk2,
                                               ushort* __restrict__ xr2,
                                               const float* __restrict__ g,
                                               const float* __restrict__ b,
                                               const float* __restrict__ mk,
                                               const float* __restrict__ mr) {
    const int row = blockIdx.x;
    const int t = row & (T_ - 1);
    const float* xc = in + (size_t)row * D_;
    const float* xp = in + (size_t)(row - 1) * D_;
    const int tid = threadIdx.x;
    const float c0 = xc[tid], c1 = xc[tid + 256], c2 = xc[tid + 512];
    float p0 = 0.f, p1 = 0.f, p2 = 0.f;
    if (t > 0) { p0 = xp[tid]; p1 = xp[tid + 256]; p2 = xp[tid + 512]; }
    float sc = c0 + c1 + c2, qc = c0 * c0 + c1 * c1 + c2 * c2;
    float sp = p0 + p1 + p2, qp = p0 * p0 + p1 * p1 + p2 * p2;
    #pragma unroll
    for (int off = 32; off > 0; off >>= 1) {
        sc += __shfl_down(sc, off); qc += __shfl_down(qc, off);
        sp += __shfl_down(sp, off); qp += __shfl_down(qp, off);
    }
    __shared__ float red[4][4];
    const int wid = tid >> 6;
    if ((tid & 63) == 0) { red[wid][0] = sc; red[wid][1] = qc; red[wid][2] = sp; red[wid][3] = qp; }
    __syncthreads();
    sc = red[0][0] + red[1][0] + red[2][0] + red[3][0];
    qc = red[0][1] + red[1][1] + red[2][1] + red[3][1];
    sp = red[0][2] + red[1][2] + red[2][2] + red[3][2];
    qp = red[0][3] + red[1][3] + red[2][3] + red[3][3];
    const float mc = sc * (1.0f / D_);
    const float rc = rsqrtf(qc * (1.0f / D_) - mc * mc + LN_EPS);
    const float mp = sp * (1.0f / D_);
    const float rp = rsqrtf(qp * (1.0f / D_) - mp * mp + LN_EPS);
    const size_t base = (size_t)row * D_;
    const float cv[3] = {c0, c1, c2};
    const float pv[3] = {p0, p1, p2};
    #pragma unroll
    for (int s = 0; s < 3; ++s) {
        const int d = tid + s * 256;
        const float cn = (cv[s] - mc) * rc * g[d] + b[d];
        const float pn = (t > 0) ? ((pv[s] - mp) * rp * g[d] + b[d]) : 0.0f;
        float m;
        m = mk[d]; xk2[base + d] = f2bf(cn * m + pn * (1.f - m));
        m = mr[d]; xr2[base + d] = f2bf(cn * m + pn * (1.f - m));
    }
}

// ---------------- WKV: chunked parallel scan over T (bf16 in, bf16 out) ----------------
// 512-thread blocks: NC=32 chunks x L=16 per channel -> 3072 waves = 12/CU
// (was 6/CU at NC=16xL=32). Coalescing unchanged (16-lane h-groups).
#define WKV_CH 16
#define WKV_NC 32
#define WKV_L  16

__global__ __launch_bounds__(512) void wkv_scan(const ushort* __restrict__ k,
                                                const ushort* __restrict__ v,
                                                const ushort* __restrict__ srr,
                                                const float* __restrict__ time_decay,
                                                const float* __restrict__ time_first,
                                                ushort* __restrict__ rv) {
    const int c   = threadIdx.x & (WKV_CH - 1);
    const int ch  = threadIdx.x >> 4;
    const int gch = blockIdx.x * WKV_CH + c;
    const int b = gch / H_;
    const int h = gch % H_;
    const float ed = expf(time_decay[h]);
    const float tf = time_first[h];
    const size_t base = (size_t)b * T_ * H_ + h;

    float n = 0.f, d = 0.f, m = -1e30f;
    size_t idx = base + (size_t)(ch * WKV_L) * H_;
    #pragma unroll 4
    for (int t = 0; t < WKV_L; ++t, idx += H_) {
        const float kk = bf2f(k[idx]), vv = bf2f(v[idx]);
        const float w2 = m - ed;
        const float qn = fmaxf(w2, kk);
        const float e1 = expf(w2 - qn), e2 = expf(kk - qn);
        n = e1 * n + e2 * vv;
        d = e1 * d + e2;
        m = qn;
    }

    __shared__ float sn[WKV_NC][WKV_CH], sd[WKV_NC][WKV_CH], sm[WKV_NC][WKV_CH];
    sn[ch][c] = n; sd[ch][c] = d; sm[ch][c] = m;
    __syncthreads();

    if (ch == 0) {
        float pn = 0.f, pd = 0.f, pm = -1e30f;
        #pragma unroll
        for (int j = 0; j < WKV_NC; ++j) {
            const float nn = sn[j][c], dd = sd[j][c], m2 = sm[j][c];
            sn[j][c] = pn; sd[j][c] = pd; sm[j][c] = pm;
            const float w2 = pm - ed * (float)WKV_L;
            const float mm = fmaxf(w2, m2);
            const float e1 = expf(w2 - mm), e2 = expf(m2 - mm);
            pn = e1 * pn + e2 * nn;
            pd = e1 * pd + e2 * dd;
            pm = mm;
        }
    }
    __syncthreads();

    n = sn[ch][c]; d = sd[ch][c]; m = sm[ch][c];
    idx = base + (size_t)(ch * WKV_L) * H_;
    #pragma unroll 4
    for (int t = 0; t < WKV_L; ++t, idx += H_) {
        const float kk = bf2f(k[idx]), vv = bf2f(v[idx]), ss = bf2f(srr[idx]);
        const float w  = tf + kk;
        const float qq = fmaxf(m, w);
        const float e1 = expf(m - qq), e2 = expf(w - qq);
        const float wkvv = (e1 * n + e2 * vv) / (e1 * d + e2);
        rv[idx] = f2bf(ss * wkvv);
        const float w2 = m - ed;
        const float qn = fmaxf(w2, kk);
        const float a  = expf(w2 - qn), bb = expf(kk - qn);
        n = a * n + bb * vv;
        d = a * d + bb;
        m = qn;
    }
}

// ================= GEMM core (2-barrier dbuf, m97 structure) — KVR / RELU2 =================
template <int BM, int NF>
__device__ __forceinline__ void run_gemm(const ushort* __restrict__ A,
                                         const ushort* __restrict__ Bt,
                                         int K, int bm, int bn,
                                         ushort* As, ushort* Bs,
                                         f32x4 (&acc)[BM / 32][NF], int t) {
    constexpr int MF = BM / 32;
    constexpr int BN = NF * 32;
    constexpr int ASTRIDE = BM * 64;
    constexpr int BSTRIDE = BN * 64;
    const int l = t & 63, wid = t >> 6;
    const int wr = wid >> 1, wc = wid & 1;
    const int lr = l & 15, lg = l >> 4;
    const int l8 = l >> 3, j8 = l & 7;
    const int gcol = ((j8 ^ l8) << 3);
    const int rsw = lr & 7;

    auto STAGE = [&](int buf, int k0) {
        #pragma unroll
        for (int p = 0; p < MF; ++p) {
            const int r = wid * (BM / 4) + p * 8 + l8;
            GLOAD_LDS16(A + (size_t)(bm + r) * K + k0 + gcol,
                        As + buf * ASTRIDE + (wid * (BM / 4) + p * 8) * 64);
        }
        #pragma unroll
        for (int p = 0; p < NF; ++p) {
            const int r = wid * (BN / 4) + p * 8 + l8;
            GLOAD_LDS16(Bt + (size_t)(bn + r) * K + k0 + gcol,
                        Bs + buf * BSTRIDE + (wid * (BN / 4) + p * 8) * 64);
        }
    };

    STAGE(0, 0);
    const int nt = K >> 6;
    int cur = 0;
    for (int it = 0; it < nt; ++it) {
        if (it + 1 < nt) {
            STAGE(cur ^ 1, (it + 1) << 6);
            constexpr int VC = MF + NF;   // just-issued stage stays in flight
            if constexpr (VC == 4)      asm volatile("s_waitcnt vmcnt(4)" ::: "memory");
            else if constexpr (VC == 5) asm volatile("s_waitcnt vmcnt(5)" ::: "memory");
            else if constexpr (VC == 6) asm volatile("s_waitcnt vmcnt(6)" ::: "memory");
            else                        asm volatile("s_waitcnt vmcnt(8)" ::: "memory");
        } else {
            asm volatile("s_waitcnt vmcnt(0)" ::: "memory");
        }
        __builtin_amdgcn_sched_barrier(0);
        __builtin_amdgcn_s_barrier();
        const ushort* Ab = As + cur * ASTRIDE;
        const ushort* Bb = Bs + cur * BSTRIDE;
        #pragma unroll
        for (int ks = 0; ks < 2; ++ks) {
            const int cidx = ((ks * 4 + lg) ^ rsw) << 3;
            bf16x8 af[MF], bfr[NF];
            #pragma unroll
            for (int mf = 0; mf < MF; ++mf)
                af[mf] = *(const bf16x8*)(Ab + (wr * (BM / 2) + mf * 16 + lr) * 64 + cidx);
            #pragma unroll
            for (int nf = 0; nf < NF; ++nf)
                bfr[nf] = *(const bf16x8*)(Bb + (wc * (BN / 2) + nf * 16 + lr) * 64 + cidx);
            #pragma unroll
            for (int mf = 0; mf < MF; ++mf)
                #pragma unroll
                for (int nf = 0; nf < NF; ++nf)
                    acc[mf][nf] = __builtin_amdgcn_mfma_f32_16x16x32_bf16(
                        af[mf], bfr[nf], acc[mf][nf], 0, 0, 0);
        }
        __builtin_amdgcn_s_barrier();   // readers done before next iter overwrites
        cur ^= 1;
    }
}

// ================= single-barrier triple-buffered core (64x64: ADDX, kv_sigmul) ==========
// Proven round 4: one s_barrier per K-step; buf X staged at X-1, read at X,
// overwritten at X+2 (safe: overwriter passed barrier X+1, readers retired).
template <int BM, int NF>
__device__ __forceinline__ void run_gemm_sb(const ushort* __restrict__ A,
                                            const ushort* __restrict__ Bt,
                                            int K, int bm, int bn,
                                            ushort* As, ushort* Bs,
                                            f32x4 (&acc)[BM / 32][NF], int t) {
    constexpr int MF = BM / 32;
    constexpr int BN = NF * 32;
    constexpr int ASTRIDE = BM * 64;
    constexpr int BSTRIDE = BN * 64;
    const int l = t & 63, wid = t >> 6;
    const int wr = wid >> 1, wc = wid & 1;
    const int lr = l & 15, lg = l >> 4;
    const int l8 = l >> 3, j8 = l & 7;
    const int gcol = ((j8 ^ l8) << 3);
    const int rsw = lr & 7;

    auto STAGE = [&](int buf, int k0) {
        #pragma unroll
        for (int p = 0; p < MF; ++p) {
            const int r = wid * (BM / 4) + p * 8 + l8;
            GLOAD_LDS16(A + (size_t)(bm + r) * K + k0 + gcol,
                        As + buf * ASTRIDE + (wid * (BM / 4) + p * 8) * 64);
        }
        #pragma unroll
        for (int p = 0; p < NF; ++p) {
            const int r = wid * (BN / 4) + p * 8 + l8;
            GLOAD_LDS16(Bt + (size_t)(bn + r) * K + k0 + gcol,
                        Bs + buf * BSTRIDE + (wid * (BN / 4) + p * 8) * 64);
        }
    };

    STAGE(0, 0);
    const int nt = K >> 6;
    int cur = 0;
    for (int it = 0; it < nt; ++it) {
        if (it + 1 < nt) {
            int nb = cur + 1; if (nb == 3) nb = 0;
            STAGE(nb, (it + 1) << 6);
            constexpr int VC = MF + NF;
            if constexpr (VC == 4)      asm volatile("s_waitcnt vmcnt(4)" ::: "memory");
            else if constexpr (VC == 5) asm volatile("s_waitcnt vmcnt(5)" ::: "memory");
            else if constexpr (VC == 6) asm volatile("s_waitcnt vmcnt(6)" ::: "memory");
            else                        asm volatile("s_waitcnt vmcnt(8)" ::: "memory");
        } else {
            asm volatile("s_waitcnt vmcnt(0)" ::: "memory");
        }
        __builtin_amdgcn_sched_barrier(0);
        __builtin_amdgcn_s_barrier();
        __builtin_amdgcn_sched_barrier(0);   // pin ds_reads after the rendezvous
        const ushort* Ab = As + cur * ASTRIDE;
        const ushort* Bb = Bs + cur * BSTRIDE;
        #pragma unroll
        for (int ks = 0; ks < 2; ++ks) {
            const int cidx = ((ks * 4 + lg) ^ rsw) << 3;
            bf16x8 af[MF], bfr[NF];
            #pragma unroll
            for (int mf = 0; mf < MF; ++mf)
                af[mf] = *(const bf16x8*)(Ab + (wr * (BM / 2) + mf * 16 + lr) * 64 + cidx);
            #pragma unroll
            for (int nf = 0; nf < NF; ++nf)
                bfr[nf] = *(const bf16x8*)(Bb + (wc * (BN / 2) + nf * 16 + lr) * 64 + cidx);
            #pragma unroll
            for (int mf = 0; mf < MF; ++mf)
                #pragma unroll
                for (int nf = 0; nf < NF; ++nf)
                    acc[mf][nf] = __builtin_amdgcn_mfma_f32_16x16x32_bf16(
                        af[mf], bfr[nf], acc[mf][nf], 0, 0, 0);
        }
        cur += 1; if (cur == 3) cur = 0;
    }
}

enum { EPI_KVR = 0, EPI_ADDX = 1, EPI_RELU2 = 2 };

template <int EPI, int BM, int BN>
__global__ __launch_bounds__(256) void hgemm(const ushort* __restrict__ Abase,
                                             const ushort* __restrict__ Wbase,
                                             void* __restrict__ Cbase,
                                             const float* __restrict__ aux1,
                                             int M, int N, int K) {
    constexpr int NF = BN / 32;
    constexpr int MF = BM / 32;
    constexpr bool SB = (BN == 64);          // single-barrier 3-buf for 64x64
    __shared__ __align__(16) ushort As[(SB ? 3 : 2) * BM * 64];
    __shared__ __align__(16) ushort Bs[(SB ? 3 : 2) * BN * 64];
    const int t = threadIdx.x;
    int lin = blockIdx.y * gridDim.x + blockIdx.x;
    const int q = (gridDim.x * gridDim.y) >> 3;
    lin = (lin & 7) * q + (lin >> 3);
    const int bn = (lin % gridDim.x) * BN;
    const int bm = (lin / gridDim.x) * BM;
    const int z = blockIdx.z;

    const ushort* A  = Abase;
    const ushort* Bt = Wbase;
    float*  Cf = (float*)Cbase;
    ushort* Cu = (ushort*)Cbase;
    if (EPI == EPI_KVR) {
        A  += (size_t)z * ((size_t)M * K);
        Bt += (size_t)z * ((size_t)N * K);
        Cu += (size_t)z * ((size_t)M * N);
    }

    f32x4 acc[MF][NF];
    #pragma unroll
    for (int i = 0; i < MF; ++i)
        #pragma unroll
        for (int j = 0; j < NF; ++j) acc[i][j] = (f32x4){0.f, 0.f, 0.f, 0.f};

    if constexpr (SB)
        run_gemm_sb<BM, NF>(A, Bt, K, bm, bn, As, Bs, acc, t);
    else
        run_gemm<BM, NF>(A, Bt, K, bm, bn, As, Bs, acc, t);

    const int l = t & 63, wid = t >> 6;
    const int wr = wid >> 1, wc = wid & 1;
    const int lr = l & 15, lg = l >> 4;
    #pragma unroll
    for (int mf = 0; mf < MF; ++mf) {
        #pragma unroll
        for (int nf = 0; nf < NF; ++nf) {
            const f32x4 a = acc[mf][nf];
            #pragma unroll
            for (int j = 0; j < 4; ++j) {
                const int row = bm + wr * (BM / 2) + mf * 16 + lg * 4 + j;
                const int col = bn + wc * (BN / 2) + nf * 16 + lr;
                const size_t idx = (size_t)row * N + col;
                const float vacc = a[j];
                if (EPI == EPI_KVR) {
                    Cu[idx] = f2bf((z == 2) ? 1.0f / (1.0f + expf(-vacc)) : vacc);
                } else if (EPI == EPI_ADDX) {
                    Cf[idx] = aux1[idx] + vacc;
                } else {  // EPI_RELU2
                    const float r = fmaxf(vacc, 0.0f);
                    Cu[idx] = f2bf(r * r);
                }
            }
        }
    }
}

// ---- fused: out = ymid + sigmoid(xr2 @ WcR) * (h1 @ WcV) ----
// 64x64 tile (grid 768 = 3 blocks/CU), 4-wave single-barrier 3-buf core.
// Round-4/8 verified best: 42.6 us = LDS-port roofline (84.5 B/cy measured
// vs 85 B/cy ds_read_b128 ceiling). All wave-tile growth paths falsified
// (r1 grid-collapse, r3/r7 HBM-blowup, r6 overlap-loss, r9 latency-bound).
__global__ __launch_bounds__(256) void kv_sigmul(const ushort* __restrict__ h1,
                                                 const ushort* __restrict__ wtCV,
                                                 const ushort* __restrict__ xr2,
                                                 const ushort* __restrict__ wtCR,
                                                 const float* __restrict__ ymid,
                                                 float* __restrict__ out) {
    __shared__ __align__(16) ushort As[3 * 64 * 64];
    __shared__ __align__(16) ushort Bs[3 * 64 * 64];
    const int t = threadIdx.x;
    int lin = blockIdx.y * gridDim.x + blockIdx.x;
    const int q = (gridDim.x * gridDim.y) >> 3;
    lin = (lin & 7) * q + (lin >> 3);
    const int bn = (lin % gridDim.x) * 64;
    const int bm = (lin / gridDim.x) * 64;

    f32x4 acc1[2][2], acc2[2][2];
    #pragma unroll
    for (int i = 0; i < 2; ++i)
        #pragma unroll
        for (int j = 0; j < 2; ++j) {
            acc1[i][j] = (f32x4){0.f, 0.f, 0.f, 0.f};
            acc2[i][j] = (f32x4){0.f, 0.f, 0.f, 0.f};
        }

    run_gemm_sb<64, 2>(h1, wtCV, 3072, bm, bn, As, Bs, acc1, t);   // kv
    __syncthreads();   // isolate buffer reuse between the two GEMMs
    run_gemm_sb<64, 2>(xr2, wtCR, 768, bm, bn, As, Bs, acc2, t);   // recept

    const int l = t & 63, wid = t >> 6;
    const int wr = wid >> 1, wc = wid & 1;
    const int lr = l & 15, lg = l >> 4;
    #pragma unroll
    for (int mf = 0; mf < 2; ++mf) {
        #pragma unroll
        for (int nf = 0; nf < 2; ++nf) {
            #pragma unroll
            for (int j = 0; j < 4; ++j) {
                const int row = bm + wr * 32 + mf * 16 + lg * 4 + j;
                const int col = bn + wc * 32 + nf * 16 + lr;
                const size_t idx = (size_t)row * D_ + col;
                const float sig = 1.0f / (1.0f + expf(-acc2[mf][nf][j]));
                out[idx] = ymid[idx] + sig * acc1[mf][nf][j];
            }
        }
    }
}

extern "C" void kernel_launch(void* const* d_in, const int* in_sizes, int n_in,
                              void* d_out, int out_size, void* d_ws, size_t ws_size,
                              hipStream_t stream) {
    const float* x          = (const float*)d_in[0];
    const float* ln1_g      = (const float*)d_in[1];
    const float* ln1_b      = (const float*)d_in[2];
    const float* ln2_g      = (const float*)d_in[3];
    const float* ln2_b      = (const float*)d_in[4];
    const float* tm_mix_k   = (const float*)d_in[5];
    const float* tm_mix_v   = (const float*)d_in[6];
    const float* tm_mix_r   = (const float*)d_in[7];
    const float* tm_key_w   = (const float*)d_in[8];
    const float* tm_value_w = (const float*)d_in[9];
    const float* tm_rec_w   = (const float*)d_in[10];
    const float* time_decay = (const float*)d_in[11];
    const float* time_first = (const float*)d_in[12];
    const float* out_w      = (const float*)d_in[13];
    const float* cm_mix_k   = (const float*)d_in[14];
    const float* cm_mix_r   = (const float*)d_in[15];
    const float* cm_key_w   = (const float*)d_in[16];
    const float* cm_value_w = (const float*)d_in[17];
    const float* cm_rec_w   = (const float*)d_in[18];
    float* out = (float*)d_out;

    const size_t SZ = (size_t)BT_ * D_;
    float* wsf = (float*)d_ws;
    float* ymid = wsf;                  // [BT,D] fp32
    ushort* ub = (ushort*)(wsf + SZ);
    ushort* a0 = ub;                    // xk, later rv
    ushort* a1 = ub + SZ;               // xv, later xk2
    ushort* a2 = ub + 2 * SZ;           // xr, later xr2
    ushort* h1 = ub + 3 * SZ;           // [BT,3072] bf16
    ushort* kvsr = ub + 7 * SZ;         // k,v,sr bf16 [3][BT*H]
    ushort* wt = ub + 10 * SZ;
    const size_t W66  = (size_t)768 * 768;
    const size_t WBIG = (size_t)768 * 3072;
    ushort* wtK  = wt;
    ushort* wtV  = wt + W66;
    ushort* wtR  = wt + 2 * W66;
    ushort* wtO  = wt + 3 * W66;
    ushort* wtCR = wt + 4 * W66;
    ushort* wtCK = wt + 5 * W66;        // [3072][768]
    ushort* wtCV = wt + 5 * W66 + WBIG; // [768][3072]

    PrepArgs pa;
    pa.x = x; pa.g = ln1_g; pa.b = ln1_b;
    pa.mk = tm_mix_k; pa.mv = tm_mix_v; pa.mr = tm_mix_r;
    pa.xk = a0; pa.xv = a1; pa.xr = a2;
    pa.ws[0] = tm_key_w;   pa.wd[0] = wtK;
    pa.ws[1] = tm_value_w; pa.wd[1] = wtV;
    pa.ws[2] = tm_rec_w;   pa.wd[2] = wtR;
    pa.ws[3] = out_w;      pa.wd[3] = wtO;
    pa.ws[4] = cm_rec_w;   pa.wd[4] = wtCR;
    pa.ws[5] = cm_key_w;   pa.wd[5] = wtCK;
    pa.ws[6] = cm_value_w; pa.wd[6] = wtCV;

    // 1. prep: LN1+time-mix + all weight transposes (one dispatch)
    prep<<<BT_ + 2880 + 2304 + 2304, 256, 0, stream>>>(pa);
    // 2. fused k/v/sr GEMM (z=0,1,2), bf16 out   [64x128 tile: grid 6x64x3 = 1152]
    hgemm<EPI_KVR, 64, 128><<<dim3(6, 64, 3), 256, 0, stream>>>(a0, wtK, kvsr, nullptr, BT_, 768, 768);
    // 3. WKV parallel scan -> rv = sr*wkv (bf16)  [512 thr, NC=32 -> 12 waves/CU]
    wkv_scan<<<(B_ * H_) / WKV_CH, 512, 0, stream>>>(kvsr, kvsr + SZ, kvsr + 2 * SZ,
                                                     time_decay, time_first, a0);
    // 4. y_mid = x + rv @ out_w                   [grid 768, 64x64 single-barrier]
    hgemm<EPI_ADDX, 64, 64><<<dim3(12, 64), 256, 0, stream>>>(a0, wtO, ymid, x, BT_, 768, 768);
    // 5. LN2 + channel-mix -> bf16 xk2/xr2
    ln_cmix<<<BT_, 256, 0, stream>>>(ymid, a1, a2, ln2_g, ln2_b, cm_mix_k, cm_mix_r);
    // 6. h1 = relu(xk2 @ cm_key)^2 (bf16)         [grid 24x64 = 1536, 64x128 dbuf]
    hgemm<EPI_RELU2, 64, 128><<<dim3(24, 64), 256, 0, stream>>>(a1, wtCK, h1, nullptr, BT_, 3072, 768);
    // 7. out = y_mid + sigmoid(xr2 @ cm_rec) * (h1 @ cm_value)   [grid 12x64 = 768]
    kv_sigmul<<<dim3(12, 64), 256, 0, stream>>>(h1, wtCV, a2, wtCR, ymid, out);
}

// Round 11
// 159.086 us; speedup vs baseline: 1.0615x; 1.0057x over previous
//
#include <hip/hip_runtime.h>
#include <cstdint>
#include <cstddef>

#define B_ 8
#define T_ 512
#define D_ 768
#define H_ 768
#define BT_ 4096
#define LN_EPS 1e-3f

typedef short bf16x8 __attribute__((ext_vector_type(8)));
typedef float f32x4 __attribute__((ext_vector_type(4)));

__device__ __forceinline__ ushort f2bf(float f) {
    union { float f; unsigned u; } x; x.f = f;
    unsigned r = (x.u + 0x7FFFu + ((x.u >> 16) & 1u)) >> 16;
    return (ushort)r;
}
__device__ __forceinline__ float bf2f(ushort u) {
    union { unsigned u; float f; } x; x.u = ((unsigned)u) << 16;
    return x.f;
}

#define GLOAD_LDS16(gp, lp)                                                        \
    __builtin_amdgcn_global_load_lds((const __attribute__((address_space(1))) void*)(gp), \
                                     (__attribute__((address_space(3))) void*)(lp), 16, 0, 0)

// ================= prep: ln_tmix (blocks 0..4095) + 7 weight transposes =================
// LN rows: float4 loads / ushort4 stores (192 active lanes; G13).
// Transposes: 64k x 32n tiles -> transposed rows are 128 B (full L2 line),
// written as ushort2/lane (was 64 B half-line segments).
struct PrepArgs {
    const float *x, *g, *b, *mk, *mv, *mr;
    ushort *xk, *xv, *xr;
    const float* ws[7];   // 5x 768x768, cm_key(768x3072), cm_value(3072x768)
    ushort* wd[7];
};

__global__ __launch_bounds__(256) void prep(PrepArgs a) {
    __shared__ float tl[64][33];
    __shared__ float red[4][4];
    int bid = blockIdx.x;
    const int tid = threadIdx.x;
    if (bid < BT_) {
        const int row = bid;
        const int t = row & (T_ - 1);
        const float* xc = a.x + (size_t)row * D_;
        const float* xp = a.x + (size_t)(row - 1) * D_;
        float4 c4 = {0.f, 0.f, 0.f, 0.f}, p4 = {0.f, 0.f, 0.f, 0.f};
        if (tid < 192) {
            c4 = *(const float4*)(xc + 4 * tid);
            if (t > 0) p4 = *(const float4*)(xp + 4 * tid);
        }
        float sc = c4.x + c4.y + c4.z + c4.w;
        float qc = c4.x * c4.x + c4.y * c4.y + c4.z * c4.z + c4.w * c4.w;
        float sp = p4.x + p4.y + p4.z + p4.w;
        float qp = p4.x * p4.x + p4.y * p4.y + p4.z * p4.z + p4.w * p4.w;
        #pragma unroll
        for (int off = 32; off > 0; off >>= 1) {
            sc += __shfl_down(sc, off); qc += __shfl_down(qc, off);
            sp += __shfl_down(sp, off); qp += __shfl_down(qp, off);
        }
        const int wid = tid >> 6;
        if ((tid & 63) == 0) { red[wid][0] = sc; red[wid][1] = qc; red[wid][2] = sp; red[wid][3] = qp; }
        __syncthreads();
        sc = red[0][0] + red[1][0] + red[2][0] + red[3][0];
        qc = red[0][1] + red[1][1] + red[2][1] + red[3][1];
        sp = red[0][2] + red[1][2] + red[2][2] + red[3][2];
        qp = red[0][3] + red[1][3] + red[2][3] + red[3][3];
        const float mc = sc * (1.0f / D_);
        const float rc = rsqrtf(qc * (1.0f / D_) - mc * mc + LN_EPS);
        const float mp = sp * (1.0f / D_);
        const float rp = rsqrtf(qp * (1.0f / D_) - mp * mp + LN_EPS);
        if (tid < 192) {
            const size_t base = (size_t)row * D_ + 4 * tid;
            const float4 g4 = *(const float4*)(a.g + 4 * tid);
            const float4 b4 = *(const float4*)(a.b + 4 * tid);
            const float4 mk4 = *(const float4*)(a.mk + 4 * tid);
            const float4 mv4 = *(const float4*)(a.mv + 4 * tid);
            const float4 mr4 = *(const float4*)(a.mr + 4 * tid);
            const float cv[4] = {c4.x, c4.y, c4.z, c4.w};
            const float pv[4] = {p4.x, p4.y, p4.z, p4.w};
            const float gv[4] = {g4.x, g4.y, g4.z, g4.w};
            const float bv[4] = {b4.x, b4.y, b4.z, b4.w};
            const float kv[4] = {mk4.x, mk4.y, mk4.z, mk4.w};
            const float vv[4] = {mv4.x, mv4.y, mv4.z, mv4.w};
            const float rv[4] = {mr4.x, mr4.y, mr4.z, mr4.w};
            ushort4 uk, uv, ur;
            ushort* pk = (ushort*)&uk;
            ushort* pvv = (ushort*)&uv;
            ushort* pr = (ushort*)&ur;
            #pragma unroll
            for (int j = 0; j < 4; ++j) {
                const float cn = (cv[j] - mc) * rc * gv[j] + bv[j];
                const float pn = (t > 0) ? ((pv[j] - mp) * rp * gv[j] + bv[j]) : 0.0f;
                pk[j]  = f2bf(cn * kv[j] + pn * (1.f - kv[j]));
                pvv[j] = f2bf(cn * vv[j] + pn * (1.f - vv[j]));
                pr[j]  = f2bf(cn * rv[j] + pn * (1.f - rv[j]));
            }
            *(ushort4*)(a.xk + base) = uk;
            *(ushort4*)(a.xv + base) = uv;
            *(ushort4*)(a.xr + base) = ur;
        }
        return;
    }
    bid -= BT_;
    int z, K, N, n0, k0;
    if (bid < 1440) {
        z = bid / 288; const int i = bid % 288;
        K = 768; N = 768; n0 = (i % 24) * 32; k0 = (i / 24) * 64;
    } else if (bid < 1440 + 1152) {
        z = 5; const int i = bid - 1440;
        K = 768; N = 3072; n0 = (i % 96) * 32; k0 = (i / 96) * 64;
    } else {
        z = 6; const int i = bid - 2592;
        K = 3072; N = 768; n0 = (i % 24) * 32; k0 = (i / 24) * 64;
    }
    const float* W = a.ws[z];
    ushort* WT = a.wd[z];
    const int tx = tid & 31, ty = tid >> 5;   // ty in 0..7
    #pragma unroll
    for (int i = 0; i < 8; ++i)
        tl[ty + i * 8][tx] = W[(size_t)(k0 + ty + i * 8) * N + n0 + tx];
    __syncthreads();
    #pragma unroll
    for (int i = 0; i < 4; ++i) {
        const int r = ty + i * 8;             // n-offset 0..31
        ushort2 u;
        u.x = f2bf(tl[2 * tx][r]);            // 2-way LDS bank alias (free, m136)
        u.y = f2bf(tl[2 * tx + 1][r]);
        *(ushort2*)(WT + (size_t)(n0 + r) * K + k0 + 2 * tx) = u;
    }
}

// ---------------- fused LN2 + channel-mix: emits bf16 xk2/xr2 ----------------
// float4 loads / ushort4 stores (192 active lanes of 256).
__global__ __launch_bounds__(256) void ln_cmix(const float* __restrict__ in,
                                               ushort* __restrict__ xk2,
                                               ushort* __restrict__ xr2,
                                               const float* __restrict__ g,
                                               const float* __restrict__ b,
                                               const float* __restrict__ mk,
                                               const float* __restrict__ mr) {
    const int row = blockIdx.x;
    const int t = row & (T_ - 1);
    const float* xc = in + (size_t)row * D_;
    const float* xp = in + (size_t)(row - 1) * D_;
    const int tid = threadIdx.x;
    float4 c4 = {0.f, 0.f, 0.f, 0.f}, p4 = {0.f, 0.f, 0.f, 0.f};
    if (tid < 192) {
        c4 = *(const float4*)(xc + 4 * tid);
        if (t > 0) p4 = *(const float4*)(xp + 4 * tid);
    }
    float sc = c4.x + c4.y + c4.z + c4.w;
    float qc = c4.x * c4.x + c4.y * c4.y + c4.z * c4.z + c4.w * c4.w;
    float sp = p4.x + p4.y + p4.z + p4.w;
    float qp = p4.x * p4.x + p4.y * p4.y + p4.z * p4.z + p4.w * p4.w;
    #pragma unroll
    for (int off = 32; off > 0; off >>= 1) {
        sc += __shfl_down(sc, off); qc += __shfl_down(qc, off);
        sp += __shfl_down(sp, off); qp += __shfl_down(qp, off);
    }
    __shared__ float red[4][4];
    const int wid = tid >> 6;
    if ((tid & 63) == 0) { red[wid][0] = sc; red[wid][1] = qc; red[wid][2] = sp; red[wid][3] = qp; }
    __syncthreads();
    sc = red[0][0] + red[1][0] + red[2][0] + red[3][0];
    qc = red[0][1] + red[1][1] + red[2][1] + red[3][1];
    sp = red[0][2] + red[1][2] + red[2][2] + red[3][2];
    qp = red[0][3] + red[1][3] + red[2][3] + red[3][3];
    const float mc = sc * (1.0f / D_);
    const float rc = rsqrtf(qc * (1.0f / D_) - mc * mc + LN_EPS);
    const float mp = sp * (1.0f / D_);
    const float rp = rsqrtf(qp * (1.0f / D_) - mp * mp + LN_EPS);
    if (tid < 192) {
        const size_t base = (size_t)row * D_ + 4 * tid;
        const float4 g4 = *(const float4*)(g + 4 * tid);
        const float4 b4 = *(const float4*)(b + 4 * tid);
        const float4 mk4 = *(const float4*)(mk + 4 * tid);
        const float4 mr4 = *(const float4*)(mr + 4 * tid);
        const float cv[4] = {c4.x, c4.y, c4.z, c4.w};
        const float pv[4] = {p4.x, p4.y, p4.z, p4.w};
        const float gv[4] = {g4.x, g4.y, g4.z, g4.w};
        const float bv[4] = {b4.x, b4.y, b4.z, b4.w};
        const float kv[4] = {mk4.x, mk4.y, mk4.z, mk4.w};
        const float rv[4] = {mr4.x, mr4.y, mr4.z, mr4.w};
        ushort4 uk, ur;
        ushort* pk = (ushort*)&uk;
        ushort* pr = (ushort*)&ur;
        #pragma unroll
        for (int j = 0; j < 4; ++j) {
            const float cn = (cv[j] - mc) * rc * gv[j] + bv[j];
            const float pn = (t > 0) ? ((pv[j] - mp) * rp * gv[j] + bv[j]) : 0.0f;
            pk[j] = f2bf(cn * kv[j] + pn * (1.f - kv[j]));
            pr[j] = f2bf(cn * rv[j] + pn * (1.f - rv[j]));
        }
        *(ushort4*)(xk2 + base) = uk;
        *(ushort4*)(xr2 + base) = ur;
    }
}

// ---------------- WKV: chunked parallel scan over T (bf16 in, bf16 out) ----------------
#define WKV_CH 16
#define WKV_NC 16
#define WKV_L  32

__global__ __launch_bounds__(256) void wkv_scan(const ushort* __restrict__ k,
                                                const ushort* __restrict__ v,
                                                const ushort* __restrict__ srr,
                                                const float* __restrict__ time_decay,
                                                const float* __restrict__ time_first,
                                                ushort* __restrict__ rv) {
    const int c   = threadIdx.x & (WKV_CH - 1);
    const int ch  = threadIdx.x >> 4;
    const int gch = blockIdx.x * WKV_CH + c;
    const int b = gch / H_;
    const int h = gch % H_;
    const float ed = expf(time_decay[h]);
    const float tf = time_first[h];
    const size_t base = (size_t)b * T_ * H_ + h;

    float n = 0.f, d = 0.f, m = -1e30f;
    size_t idx = base + (size_t)(ch * WKV_L) * H_;
    #pragma unroll 4
    for (int t = 0; t < WKV_L; ++t, idx += H_) {
        const float kk = bf2f(k[idx]), vv = bf2f(v[idx]);
        const float w2 = m - ed;
        const float qn = fmaxf(w2, kk);
        const float e1 = expf(w2 - qn), e2 = expf(kk - qn);
        n = e1 * n + e2 * vv;
        d = e1 * d + e2;
        m = qn;
    }

    __shared__ float sn[WKV_NC][WKV_CH], sd[WKV_NC][WKV_CH], sm[WKV_NC][WKV_CH];
    sn[ch][c] = n; sd[ch][c] = d; sm[ch][c] = m;
    __syncthreads();

    if (ch == 0) {
        float pn = 0.f, pd = 0.f, pm = -1e30f;
        #pragma unroll
        for (int j = 0; j < WKV_NC; ++j) {
            const float nn = sn[j][c], dd = sd[j][c], m2 = sm[j][c];
            sn[j][c] = pn; sd[j][c] = pd; sm[j][c] = pm;
            const float w2 = pm - ed * (float)WKV_L;
            const float mm = fmaxf(w2, m2);
            const float e1 = expf(w2 - mm), e2 = expf(m2 - mm);
            pn = e1 * pn + e2 * nn;
            pd = e1 * pd + e2 * dd;
            pm = mm;
        }
    }
    __syncthreads();

    n = sn[ch][c]; d = sd[ch][c]; m = sm[ch][c];
    idx = base + (size_t)(ch * WKV_L) * H_;
    #pragma unroll 4
    for (int t = 0; t < WKV_L; ++t, idx += H_) {
        const float kk = bf2f(k[idx]), vv = bf2f(v[idx]), ss = bf2f(srr[idx]);
        const float w  = tf + kk;
        const float qq = fmaxf(m, w);
        const float e1 = expf(m - qq), e2 = expf(w - qq);
        const float wkvv = (e1 * n + e2 * vv) / (e1 * d + e2);
        rv[idx] = f2bf(ss * wkvv);
        const float w2 = m - ed;
        const float qn = fmaxf(w2, kk);
        const float a  = expf(w2 - qn), bb = expf(kk - qn);
        n = a * n + bb * vv;
        d = a * d + bb;
        m = qn;
    }
}

// ================= GEMM core (2-barrier dbuf, m97 structure) — KVR / RELU2 =================
template <int BM, int NF>
__device__ __forceinline__ void run_gemm(const ushort* __restrict__ A,
                                         const ushort* __restrict__ Bt,
                                         int K, int bm, int bn,
                                         ushort* As, ushort* Bs,
                                         f32x4 (&acc)[BM / 32][NF], int t) {
    constexpr int MF = BM / 32;
    constexpr int BN = NF * 32;
    constexpr int ASTRIDE = BM * 64;
    constexpr int BSTRIDE = BN * 64;
    const int l = t & 63, wid = t >> 6;
    const int wr = wid >> 1, wc = wid & 1;
    const int lr = l & 15, lg = l >> 4;
    const int l8 = l >> 3, j8 = l & 7;
    const int gcol = ((j8 ^ l8) << 3);
    const int rsw = lr & 7;

    auto STAGE = [&](int buf, int k0) {
        #pragma unroll
        for (int p = 0; p < MF; ++p) {
            const int r = wid * (BM / 4) + p * 8 + l8;
            GLOAD_LDS16(A + (size_t)(bm + r) * K + k0 + gcol,
                        As + buf * ASTRIDE + (wid * (BM / 4) + p * 8) * 64);
        }
        #pragma unroll
        for (int p = 0; p < NF; ++p) {
            const int r = wid * (BN / 4) + p * 8 + l8;
            GLOAD_LDS16(Bt + (size_t)(bn + r) * K + k0 + gcol,
                        Bs + buf * BSTRIDE + (wid * (BN / 4) + p * 8) * 64);
        }
    };

    STAGE(0, 0);
    const int nt = K >> 6;
    int cur = 0;
    for (int it = 0; it < nt; ++it) {
        if (it + 1 < nt) {
            STAGE(cur ^ 1, (it + 1) << 6);
            constexpr int VC = MF + NF;   // just-issued stage stays in flight
            if constexpr (VC == 4)      asm volatile("s_waitcnt vmcnt(4)" ::: "memory");
            else if constexpr (VC == 5) asm volatile("s_waitcnt vmcnt(5)" ::: "memory");
            else if constexpr (VC == 6) asm volatile("s_waitcnt vmcnt(6)" ::: "memory");
            else                        asm volatile("s_waitcnt vmcnt(8)" ::: "memory");
        } else {
            asm volatile("s_waitcnt vmcnt(0)" ::: "memory");
        }
        __builtin_amdgcn_sched_barrier(0);
        __builtin_amdgcn_s_barrier();
        const ushort* Ab = As + cur * ASTRIDE;
        const ushort* Bb = Bs + cur * BSTRIDE;
        #pragma unroll
        for (int ks = 0; ks < 2; ++ks) {
            const int cidx = ((ks * 4 + lg) ^ rsw) << 3;
            bf16x8 af[MF], bfr[NF];
            #pragma unroll
            for (int mf = 0; mf < MF; ++mf)
                af[mf] = *(const bf16x8*)(Ab + (wr * (BM / 2) + mf * 16 + lr) * 64 + cidx);
            #pragma unroll
            for (int nf = 0; nf < NF; ++nf)
                bfr[nf] = *(const bf16x8*)(Bb + (wc * (BN / 2) + nf * 16 + lr) * 64 + cidx);
            #pragma unroll
            for (int mf = 0; mf < MF; ++mf)
                #pragma unroll
                for (int nf = 0; nf < NF; ++nf)
                    acc[mf][nf] = __builtin_amdgcn_mfma_f32_16x16x32_bf16(
                        af[mf], bfr[nf], acc[mf][nf], 0, 0, 0);
        }
        __builtin_amdgcn_s_barrier();   // readers done before next iter overwrites
        cur ^= 1;
    }
}

// ================= single-barrier triple-buffered core (64x64: ADDX, kv_sigmul) ==========
// Proven round 4: one s_barrier per K-step; buf X staged at X-1, read at X,
// overwritten at X+2 (safe: overwriter passed barrier X+1, readers retired).
template <int BM, int NF>
__device__ __forceinline__ void run_gemm_sb(const ushort* __restrict__ A,
                                            const ushort* __restrict__ Bt,
                                            int K, int bm, int bn,
                                            ushort* As, ushort* Bs,
                                            f32x4 (&acc)[BM / 32][NF], int t) {
    constexpr int MF = BM / 32;
    constexpr int BN = NF * 32;
    constexpr int ASTRIDE = BM * 64;
    constexpr int BSTRIDE = BN * 64;
    const int l = t & 63, wid = t >> 6;
    const int wr = wid >> 1, wc = wid & 1;
    const int lr = l & 15, lg = l >> 4;
    const int l8 = l >> 3, j8 = l & 7;
    const int gcol = ((j8 ^ l8) << 3);
    const int rsw = lr & 7;

    auto STAGE = [&](int buf, int k0) {
        #pragma unroll
        for (int p = 0; p < MF; ++p) {
            const int r = wid * (BM / 4) + p * 8 + l8;
            GLOAD_LDS16(A + (size_t)(bm + r) * K + k0 + gcol,
                        As + buf * ASTRIDE + (wid * (BM / 4) + p * 8) * 64);
        }
        #pragma unroll
        for (int p = 0; p < NF; ++p) {
            const int r = wid * (BN / 4) + p * 8 + l8;
            GLOAD_LDS16(Bt + (size_t)(bn + r) * K + k0 + gcol,
                        Bs + buf * BSTRIDE + (wid * (BN / 4) + p * 8) * 64);
        }
    };

    STAGE(0, 0);
    const int nt = K >> 6;
    int cur = 0;
    for (int it = 0; it < nt; ++it) {
        if (it + 1 < nt) {
            int nb = cur + 1; if (nb == 3) nb = 0;
            STAGE(nb, (it + 1) << 6);
            constexpr int VC = MF + NF;
            if constexpr (VC == 4)      asm volatile("s_waitcnt vmcnt(4)" ::: "memory");
            else if constexpr (VC == 5) asm volatile("s_waitcnt vmcnt(5)" ::: "memory");
            else if constexpr (VC == 6) asm volatile("s_waitcnt vmcnt(6)" ::: "memory");
            else                        asm volatile("s_waitcnt vmcnt(8)" ::: "memory");
        } else {
            asm volatile("s_waitcnt vmcnt(0)" ::: "memory");
        }
        __builtin_amdgcn_sched_barrier(0);
        __builtin_amdgcn_s_barrier();
        __builtin_amdgcn_sched_barrier(0);   // pin ds_reads after the rendezvous
        const ushort* Ab = As + cur * ASTRIDE;
        const ushort* Bb = Bs + cur * BSTRIDE;
        #pragma unroll
        for (int ks = 0; ks < 2; ++ks) {
            const int cidx = ((ks * 4 + lg) ^ rsw) << 3;
            bf16x8 af[MF], bfr[NF];
            #pragma unroll
            for (int mf = 0; mf < MF; ++mf)
                af[mf] = *(const bf16x8*)(Ab + (wr * (BM / 2) + mf * 16 + lr) * 64 + cidx);
            #pragma unroll
            for (int nf = 0; nf < NF; ++nf)
                bfr[nf] = *(const bf16x8*)(Bb + (wc * (BN / 2) + nf * 16 + lr) * 64 + cidx);
            #pragma unroll
            for (int mf = 0; mf < MF; ++mf)
                #pragma unroll
                for (int nf = 0; nf < NF; ++nf)
                    acc[mf][nf] = __builtin_amdgcn_mfma_f32_16x16x32_bf16(
                        af[mf], bfr[nf], acc[mf][nf], 0, 0, 0);
        }
        cur += 1; if (cur == 3) cur = 0;
    }
}

enum { EPI_KVR = 0, EPI_ADDX = 1, EPI_RELU2 = 2 };

template <int EPI, int BM, int BN>
__global__ __launch_bounds__(256) void hgemm(const ushort* __restrict__ Abase,
                                             const ushort* __restrict__ Wbase,
                                             void* __restrict__ Cbase,
                                             const float* __restrict__ aux1,
                                             int M, int N, int K) {
    constexpr int NF = BN / 32;
    constexpr int MF = BM / 32;
    constexpr bool SB = (BN == 64);          // single-barrier 3-buf for 64x64
    __shared__ __align__(16) ushort As[(SB ? 3 : 2) * BM * 64];
    __shared__ __align__(16) ushort Bs[(SB ? 3 : 2) * BN * 64];
    const int t = threadIdx.x;
    int lin = blockIdx.y * gridDim.x + blockIdx.x;
    const int q = (gridDim.x * gridDim.y) >> 3;
    lin = (lin & 7) * q + (lin >> 3);
    const int bn = (lin % gridDim.x) * BN;
    const int bm = (lin / gridDim.x) * BM;
    const int z = blockIdx.z;

    const ushort* A  = Abase;
    const ushort* Bt = Wbase;
    float*  Cf = (float*)Cbase;
    ushort* Cu = (ushort*)Cbase;
    if (EPI == EPI_KVR) {
        A  += (size_t)z * ((size_t)M * K);
        Bt += (size_t)z * ((size_t)N * K);
        Cu += (size_t)z * ((size_t)M * N);
    }

    f32x4 acc[MF][NF];
    #pragma unroll
    for (int i = 0; i < MF; ++i)
        #pragma unroll
        for (int j = 0; j < NF; ++j) acc[i][j] = (f32x4){0.f, 0.f, 0.f, 0.f};

    if constexpr (SB)
        run_gemm_sb<BM, NF>(A, Bt, K, bm, bn, As, Bs, acc, t);
    else
        run_gemm<BM, NF>(A, Bt, K, bm, bn, As, Bs, acc, t);

    const int l = t & 63, wid = t >> 6;
    const int wr = wid >> 1, wc = wid & 1;
    const int lr = l & 15, lg = l >> 4;
    #pragma unroll
    for (int mf = 0; mf < MF; ++mf) {
        #pragma unroll
        for (int nf = 0; nf < NF; ++nf) {
            const f32x4 a = acc[mf][nf];
            #pragma unroll
            for (int j = 0; j < 4; ++j) {
                const int row = bm + wr * (BM / 2) + mf * 16 + lg * 4 + j;
                const int col = bn + wc * (BN / 2) + nf * 16 + lr;
                const size_t idx = (size_t)row * N + col;
                const float vacc = a[j];
                if (EPI == EPI_KVR) {
                    Cu[idx] = f2bf((z == 2) ? 1.0f / (1.0f + expf(-vacc)) : vacc);
                } else if (EPI == EPI_ADDX) {
                    Cf[idx] = aux1[idx] + vacc;
                } else {  // EPI_RELU2
                    const float r = fmaxf(vacc, 0.0f);
                    Cu[idx] = f2bf(r * r);
                }
            }
        }
    }
}

// ---- fused: out = ymid + sigmoid(xr2 @ WcR) * (h1 @ WcV) ----
// 64x64 tile (grid 768 = 3 blocks/CU), 4-wave single-barrier 3-buf core.
// Verified plateau: 42.5 us = LDS-port roofline (84.5 B/cy measured vs 85 B/cy
// ds_read_b128 ceiling). All wave-tile growth paths falsified (r1 grid-collapse,
// r3/r7 HBM-blowup, r6 overlap-loss, r9 latency-bound).
__global__ __launch_bounds__(256) void kv_sigmul(const ushort* __restrict__ h1,
                                                 const ushort* __restrict__ wtCV,
                                                 const ushort* __restrict__ xr2,
                                                 const ushort* __restrict__ wtCR,
                                                 const float* __restrict__ ymid,
                                                 float* __restrict__ out) {
    __shared__ __align__(16) ushort As[3 * 64 * 64];
    __shared__ __align__(16) ushort Bs[3 * 64 * 64];
    const int t = threadIdx.x;
    int lin = blockIdx.y * gridDim.x + blockIdx.x;
    const int q = (gridDim.x * gridDim.y) >> 3;
    lin = (lin & 7) * q + (lin >> 3);
    const int bn = (lin % gridDim.x) * 64;
    const int bm = (lin / gridDim.x) * 64;

    f32x4 acc1[2][2], acc2[2][2];
    #pragma unroll
    for (int i = 0; i < 2; ++i)
        #pragma unroll
        for (int j = 0; j < 2; ++j) {
            acc1[i][j] = (f32x4){0.f, 0.f, 0.f, 0.f};
            acc2[i][j] = (f32x4){0.f, 0.f, 0.f, 0.f};
        }

    run_gemm_sb<64, 2>(h1, wtCV, 3072, bm, bn, As, Bs, acc1, t);   // kv
    __syncthreads();   // isolate buffer reuse between the two GEMMs
    run_gemm_sb<64, 2>(xr2, wtCR, 768, bm, bn, As, Bs, acc2, t);   // recept

    const int l = t & 63, wid = t >> 6;
    const int wr = wid >> 1, wc = wid & 1;
    const int lr = l & 15, lg = l >> 4;
    #pragma unroll
    for (int mf = 0; mf < 2; ++mf) {
        #pragma unroll
        for (int nf = 0; nf < 2; ++nf) {
            #pragma unroll
            for (int j = 0; j < 4; ++j) {
                const int row = bm + wr * 32 + mf * 16 + lg * 4 + j;
                const int col = bn + wc * 32 + nf * 16 + lr;
                const size_t idx = (size_t)row * D_ + col;
                const float sig = 1.0f / (1.0f + expf(-acc2[mf][nf][j]));
                out[idx] = ymid[idx] + sig * acc1[mf][nf][j];
            }
        }
    }
}

extern "C" void kernel_launch(void* const* d_in, const int* in_sizes, int n_in,
                              void* d_out, int out_size, void* d_ws, size_t ws_size,
                              hipStream_t stream) {
    const float* x          = (const float*)d_in[0];
    const float* ln1_g      = (const float*)d_in[1];
    const float* ln1_b      = (const float*)d_in[2];
    const float* ln2_g      = (const float*)d_in[3];
    const float* ln2_b      = (const float*)d_in[4];
    const float* tm_mix_k   = (const float*)d_in[5];
    const float* tm_mix_v   = (const float*)d_in[6];
    const float* tm_mix_r   = (const float*)d_in[7];
    const float* tm_key_w   = (const float*)d_in[8];
    const float* tm_value_w = (const float*)d_in[9];
    const float* tm_rec_w   = (const float*)d_in[10];
    const float* time_decay = (const float*)d_in[11];
    const float* time_first = (const float*)d_in[12];
    const float* out_w      = (const float*)d_in[13];
    const float* cm_mix_k   = (const float*)d_in[14];
    const float* cm_mix_r   = (const float*)d_in[15];
    const float* cm_key_w   = (const float*)d_in[16];
    const float* cm_value_w = (const float*)d_in[17];
    const float* cm_rec_w   = (const float*)d_in[18];
    float* out = (float*)d_out;

    const size_t SZ = (size_t)BT_ * D_;
    float* wsf = (float*)d_ws;
    float* ymid = wsf;                  // [BT,D] fp32
    ushort* ub = (ushort*)(wsf + SZ);
    ushort* a0 = ub;                    // xk, later rv
    ushort* a1 = ub + SZ;               // xv, later xk2
    ushort* a2 = ub + 2 * SZ;           // xr, later xr2
    ushort* h1 = ub + 3 * SZ;           // [BT,3072] bf16
    ushort* kvsr = ub + 7 * SZ;         // k,v,sr bf16 [3][BT*H]
    ushort* wt = ub + 10 * SZ;
    const size_t W66  = (size_t)768 * 768;
    const size_t WBIG = (size_t)768 * 3072;
    ushort* wtK  = wt;
    ushort* wtV  = wt + W66;
    ushort* wtR  = wt + 2 * W66;
    ushort* wtO  = wt + 3 * W66;
    ushort* wtCR = wt + 4 * W66;
    ushort* wtCK = wt + 5 * W66;        // [3072][768]
    ushort* wtCV = wt + 5 * W66 + WBIG; // [768][3072]

    PrepArgs pa;
    pa.x = x; pa.g = ln1_g; pa.b = ln1_b;
    pa.mk = tm_mix_k; pa.mv = tm_mix_v; pa.mr = tm_mix_r;
    pa.xk = a0; pa.xv = a1; pa.xr = a2;
    pa.ws[0] = tm_key_w;   pa.wd[0] = wtK;
    pa.ws[1] = tm_value_w; pa.wd[1] = wtV;
    pa.ws[2] = tm_rec_w;   pa.wd[2] = wtR;
    pa.ws[3] = out_w;      pa.wd[3] = wtO;
    pa.ws[4] = cm_rec_w;   pa.wd[4] = wtCR;
    pa.ws[5] = cm_key_w;   pa.wd[5] = wtCK;
    pa.ws[6] = cm_value_w; pa.wd[6] = wtCV;

    // 1. prep: LN1+time-mix + all weight transposes (one dispatch)
    //    [64kx32n transpose tiles: 1440 + 1152 + 1152 = 3744 transpose blocks]
    prep<<<BT_ + 1440 + 1152 + 1152, 256, 0, stream>>>(pa);
    // 2. fused k/v/sr GEMM (z=0,1,2), bf16 out   [64x128 tile: grid 6x64x3 = 1152]
    hgemm<EPI_KVR, 64, 128><<<dim3(6, 64, 3), 256, 0, stream>>>(a0, wtK, kvsr, nullptr, BT_, 768, 768);
    // 3. WKV parallel scan -> rv = sr*wkv (bf16)
    wkv_scan<<<(B_ * H_) / WKV_CH, 256, 0, stream>>>(kvsr, kvsr + SZ, kvsr + 2 * SZ,
                                                     time_decay, time_first, a0);
    // 4. y_mid = x + rv @ out_w                   [grid 768, 64x64 single-barrier]
    hgemm<EPI_ADDX, 64, 64><<<dim3(12, 64), 256, 0, stream>>>(a0, wtO, ymid, x, BT_, 768, 768);
    // 5. LN2 + channel-mix -> bf16 xk2/xr2
    ln_cmix<<<BT_, 256, 0, stream>>>(ymid, a1, a2, ln2_g, ln2_b, cm_mix_k, cm_mix_r);
    // 6. h1 = relu(xk2 @ cm_key)^2 (bf16)         [grid 24x64 = 1536, 64x128 dbuf]
    hgemm<EPI_RELU2, 64, 128><<<dim3(24, 64), 256, 0, stream>>>(a1, wtCK, h1, nullptr, BT_, 3072, 768);
    // 7. out = y_mid + sigmoid(xr2 @ cm_rec) * (h1 @ cm_value)   [grid 12x64 = 768]
    kv_sigmul<<<dim3(12, 64), 256, 0, stream>>>(h1, wtCV, a2, wtCR, ymid, out);
}